// Round 12
// baseline (369.309 us; speedup 1.0000x reference)
//
#include <hip/hip_runtime.h>

#define NN 30000
#define NE 300000
#define HIDDEN 256

typedef __attribute__((ext_vector_type(8))) __bf16 bf16x8;
typedef __attribute__((ext_vector_type(4))) __bf16 bf16x4;
typedef __attribute__((ext_vector_type(4))) float float4v;

__device__ inline __bf16 f2bf(float f) {
  unsigned u = __builtin_bit_cast(unsigned, f);
  u += 0x7fffu + ((u >> 16) & 1u);
  unsigned short s = (unsigned short)(u >> 16);
  return __builtin_bit_cast(__bf16, s);
}
__device__ inline float bf2f(__bf16 b) {
  unsigned short s = __builtin_bit_cast(unsigned short, b);
  unsigned u = ((unsigned)s) << 16;
  return __builtin_bit_cast(float, u);
}
__device__ inline float gelu_tanh(float x) {
  float x3 = x * x * x;
  return 0.5f * x * (1.0f + tanhf(0.79788456080286536f * (x + 0.044715f * x3)));
}

// ---------------- fused prep: 7 weight transposes + ball + WeT + x->bf16 + zero ints --------
#define PREP_XB_END (1829 + (NN * 32 + 255) / 256)
__global__ __launch_bounds__(256) void prep_kernel(
    const float* __restrict__ Wq, const float* __restrict__ Wk, const float* __restrict__ Wv,
    const float* __restrict__ Wsk, const float* __restrict__ W1, const float* __restrict__ W2,
    const float* __restrict__ We, const float* __restrict__ bq, const float* __restrict__ bk,
    const float* __restrict__ bv, const float* __restrict__ x,
    __bf16* __restrict__ WTall, __bf16* __restrict__ WT1, __bf16* __restrict__ WT2,
    float* __restrict__ ball, float* __restrict__ WeT, __bf16* __restrict__ xb,
    int* __restrict__ degz) {
  const int b = blockIdx.x;
  const int tid = threadIdx.x;
  if (b < 1792) {
    const int region = b >> 8;
    const int idx = ((b & 255) << 8) | tid;  // [n(8b)|k(8b)] -> Wt[n][k]
    const int k = idx & 255, n = idx >> 8;
    float v;
    if (region == 3) {  // Wqe[k][n] on the fly: n = h*32+d
      const int h = n >> 5, d = n & 31;
      const float* wq = Wq + (size_t)k * 256 + h * 32;
      const float* we = We + (size_t)d * 256 + h * 32;
      float s = 0.f;
#pragma unroll
      for (int c = 0; c < 32; ++c) s += wq[c] * we[c];
      v = s;
    } else {
      const float* W = (region == 0) ? Wq : (region == 1) ? Wk : (region == 2) ? Wv
                     : (region == 4) ? Wsk : (region == 5) ? W1 : W2;
      v = W[(size_t)k * 256 + n];
    }
    const __bf16 bv16 = f2bf(v);
    if (region < 5) WTall[(size_t)region * 65536 + idx] = bv16;
    else if (region == 5) WT1[idx] = bv16;
    else WT2[idx] = bv16;
  } else if (b < 1797) {
    const int j = (b - 1792) * 256 + tid;
    if (j < 1280) {
      float v = 0.f;
      if (j < 256) v = bq[j];
      else if (j < 512) v = bk[j - 256];
      else if (j < 768) v = bv[j - 512];
      else if (j < 1024) {
        const int col = j - 768, h = col >> 5, d = col & 31;
        const float* bqh = bq + h * 32;
        const float* we = We + (size_t)d * 256 + h * 32;
        float s = 0.f;
#pragma unroll
        for (int c = 0; c < 32; ++c) s += bqh[c] * we[c];
        v = s;
      }
      ball[j] = v;
    }
  } else if (b < 1829) {
    const int idx = (b - 1797) * 256 + tid;  // < 8192
    const int ch = idx >> 5, d = idx & 31;
    WeT[idx] = We[(size_t)d * 256 + ch];
  } else if (b < PREP_XB_END) {
    const int t = (b - 1829) * 256 + tid;
    if (t < NN * 256 / 8) {
      const float* p = x + (size_t)t * 8;
      float4v f0 = *(const float4v*)(p);
      float4v f1 = *(const float4v*)(p + 4);
      bf16x8 o;
#pragma unroll
      for (int j = 0; j < 4; ++j) { o[j] = f2bf(f0[j]); o[j + 4] = f2bf(f1[j]); }
      *(bf16x8*)(xb + (size_t)t * 8) = o;
    }
  } else {
    const int idx = (b - PREP_XB_END) * 256 + tid;
    if (idx < 2 * NN) degz[idx] = 0;
  }
}

// ---------------- CSR build ----------------
__global__ void count_deg_kernel(const int* __restrict__ dst, int* __restrict__ deg, int E) {
  int e = blockIdx.x * 256 + threadIdx.x;
  if (e < E) atomicAdd(&deg[dst[e]], 1);
}

// fused offs: block computes its exclusive base by redundant sum of deg[0..blk*256)
// then intra-block scan. 1 kernel replaces psum+scan+offs; no cross-block sync.
__global__ __launch_bounds__(256) void offs_fused_kernel(const int* __restrict__ deg,
                                                         int* __restrict__ offs, int n) {
  __shared__ int tmp[256];
  __shared__ int sbase[4];
  const int t = threadIdx.x;
  const int lim = blockIdx.x * 256;
  int bp = 0;
  for (int idx = t; idx < lim; idx += 256) bp += deg[idx];
#pragma unroll
  for (int s = 1; s < 64; s <<= 1) bp += __shfl_xor(bp, s);
  if ((t & 63) == 0) sbase[t >> 6] = bp;
  const int i = lim + t;
  int v = (i < n) ? deg[i] : 0;
  tmp[t] = v;
  __syncthreads();
  const int base = sbase[0] + sbase[1] + sbase[2] + sbase[3];
  for (int s = 1; s < 256; s <<= 1) {
    int u = (t >= s) ? tmp[t - s] : 0;
    __syncthreads();
    tmp[t] += u;
    __syncthreads();
  }
  if (i < n) offs[i] = base + tmp[t] - v;
  if (blockIdx.x == gridDim.x - 1 && t == 0) offs[n] = NE;
}

// scatter + fused ea permute: coalesced fp32 ea read (e sequential), bf16
// convert, scattered 64B write to CSR slot (random WRITES are fire-and-forget).
__global__ void scatter_kernel(const int* __restrict__ srcIn, const int* __restrict__ dstIn,
                               const float* __restrict__ ea,
                               const int* __restrict__ offs, int* __restrict__ cursor,
                               int* __restrict__ srcs, __bf16* __restrict__ eaC, int E) {
  int e = blockIdx.x * 256 + threadIdx.x;
  if (e >= E) return;
  const float* src = ea + (size_t)e * 32;
  float4v f[8];
#pragma unroll
  for (int t = 0; t < 8; ++t) f[t] = *(const float4v*)(src + t * 4);
  int d = dstIn[e];
  int p = atomicAdd(&cursor[d], 1);
  int o = offs[d] + p;
  srcs[o] = srcIn[e];
  __bf16* dstp = eaC + (size_t)o * 32;
#pragma unroll
  for (int t = 0; t < 4; ++t) {
    bf16x8 b;
#pragma unroll
    for (int j = 0; j < 4; ++j) { b[j] = f2bf(f[t * 2][j]); b[j + 4] = f2bf(f[t * 2 + 1][j]); }
    *(bf16x8*)(dstp + t * 8) = b;
  }
}

// ---------------- MFMA GEMM v5: tileable N (TN) for occupancy ---------------
// TN=128: B-tile 67.6KB, 2 blocks/CU. TN=64: 34.8KB, 4 blocks/CU. TN=32:
// 18.4KB, 8 blocks/CU. Smaller TN = more blocks + higher residency (verified
// lever: MLP gemms 66us @TN=128 -> <61us @TN=64, mechanism = latency-bound
// at Occ 18%).
template <int GX, int EPI, int MODE, int TN>
__global__ __launch_bounds__(256) void gemm_k4(
    const __bf16* __restrict__ A, const __bf16* __restrict__ Wt,
    const float* __restrict__ bias,
    float* __restrict__ Yf, __bf16* __restrict__ Ybf,
    __bf16* __restrict__ QGp, __bf16* __restrict__ KVp,
    const float* __restrict__ resid, int M, int gyTiles) {
  constexpr int XT = (GX * 128) / TN;   // col-tiles
  constexpr int NT = TN / 16;           // MFMA col frags per wave
  constexpr int CST = TN + 4;           // C-stage stride (floats)
  constexpr size_t SM_B = (size_t)TN * 264 * 2;
  constexpr size_t SM_C = (size_t)4 * 32 * CST * 4;
  constexpr size_t SMEM = SM_B > SM_C ? SM_B : SM_C;
  __shared__ __attribute__((aligned(16))) char smem[SMEM];
  __bf16* Bs = (__bf16*)smem;
  const int bid = blockIdx.x;
  const int stripe = bid / (8 * XT);
  const int rem = bid % (8 * XT);
  const int y8 = rem % 8;   // XCD id: col-blocks of one row-stripe share an XCD
  const int xt = rem / 8;
  const int y = stripe * 8 + y8;
  if (y >= gyTiles) return;
  const int n0 = xt * TN;

  {
    const int t = threadIdx.x;
#pragma unroll
    for (int i = 0; i < TN / 8; ++i) {  // TN*32 chunks / 256 threads
      int g = i * 256 + t;
      int row = g >> 5;
      int c16 = g & 31;
      bf16x8 v = *(const bf16x8*)(Wt + (size_t)(n0 + row) * 256 + c16 * 8);
      *(bf16x8*)(Bs + row * 264 + c16 * 8) = v;
    }
  }
  __syncthreads();

  const int lane = threadIdx.x & 63;
  const int w = threadIdx.x >> 6;
  const int r = lane & 15;
  const int q = lane >> 4;
  const int mw = y * 128 + w * 32;
  int ar0 = mw + r;      if (ar0 >= M) ar0 = M - 1;
  int ar1 = mw + 16 + r; if (ar1 >= M) ar1 = M - 1;
  const int kq = q * 8;

  float4v acc[2][NT];
#pragma unroll
  for (int i = 0; i < 2; ++i)
#pragma unroll
    for (int t = 0; t < NT; ++t) acc[i][t] = (float4v){0.f, 0.f, 0.f, 0.f};

#pragma unroll
  for (int kk = 0; kk < 256; kk += 32) {
    const int ka = kk + kq;
    bf16x8 a0 = *(const bf16x8*)(A + (size_t)ar0 * 256 + ka);
    bf16x8 a1 = *(const bf16x8*)(A + (size_t)ar1 * 256 + ka);
    bf16x8 b[NT];
#pragma unroll
    for (int t = 0; t < NT; ++t)
      b[t] = *(const bf16x8*)(Bs + (t * 16 + r) * 264 + ka);
#pragma unroll
    for (int t = 0; t < NT; ++t) {
      acc[0][t] = __builtin_amdgcn_mfma_f32_16x16x32_bf16(a0, b[t], acc[0][t], 0, 0, 0);
      acc[1][t] = __builtin_amdgcn_mfma_f32_16x16x32_bf16(a1, b[t], acc[1][t], 0, 0, 0);
    }
  }
  __syncthreads();  // B-tile dead; reuse LDS as C-stage

  // stage C (fp32, stride CST) with bias/gelu applied
  float* cs = (float*)smem + w * 32 * CST;
#pragma unroll
  for (int t = 0; t < NT; ++t) {
    const int col = n0 + t * 16 + r;
    const float bb = bias ? bias[col] : 0.0f;
#pragma unroll
    for (int i2 = 0; i2 < 2; ++i2)
#pragma unroll
      for (int ii = 0; ii < 4; ++ii) {
        float v = acc[i2][t][ii] + bb;
        if constexpr (EPI == 2 || EPI == 3) v = gelu_tanh(v);
        cs[(i2 * 16 + q * 4 + ii) * CST + t * 16 + r] = v;
      }
  }

  // coalesced read-back + vector stores (per-wave region; same-wave LDS order ok)
  constexpr int NSTR = GX * 128;
  constexpr int RPI = 256 / TN;   // rows per iter
  constexpr int LPR = TN / 4;     // lanes per row
  const int p = n0 >> 8;
  const int cbase = n0 & 255;
  __bf16* dstI = (p == 0 || p == 3) ? QGp : KVp;
  const int moff = (p >= 2) ? 4 : 0;  // planes 2(V),3(G) are second member
#pragma unroll
  for (int i = 0; i < 32 / RPI; ++i) {
    const int rl = i * RPI + lane / LPR;
    const int row = mw + rl;
    const int c4 = (lane % LPR) * 4;
    float4v v = *(const float4v*)(cs + rl * CST + c4);
    if (row < M) {
      if constexpr (MODE == 1) {
        if (p == 4) {
          *(float4v*)(Yf + (size_t)row * 256 + cbase + c4) = v;
        } else {
          bf16x4 b4;
          b4[0] = f2bf(v[0]); b4[1] = f2bf(v[1]); b4[2] = f2bf(v[2]); b4[3] = f2bf(v[3]);
          const int c = cbase + c4;
          *(bf16x4*)(dstI + (size_t)row * 512 + 2 * c + moff) = b4;
        }
      } else if constexpr (EPI == 1) {
        *(float4v*)(Yf + (size_t)row * NSTR + n0 + c4) = v;
      } else if constexpr (EPI == 3) {
        float4v rr = *(const float4v*)(resid + (size_t)row * NSTR + n0 + c4);
        v[0] += rr[0]; v[1] += rr[1]; v[2] += rr[2]; v[3] += rr[3];
        *(float4v*)(Yf + (size_t)row * NSTR + n0 + c4) = v;
      } else {  // bf16 out
        bf16x4 b4;
        b4[0] = f2bf(v[0]); b4[1] = f2bf(v[1]); b4[2] = f2bf(v[2]); b4[3] = f2bf(v[3]);
        *(bf16x4*)(Ybf + (size_t)row * NSTR + n0 + c4) = b4;
      }
    }
  }
}

// ---------------- attention (v5 exact, proven 61us): 4 waves/node, direct
// per-edge srcs loads, 2-edge unroll (i, i+4), single random-gather stream
// (KV); eaC CSR-ordered sequential; exp2 with prefolded scale; wave-0 epilogue.
__global__ __launch_bounds__(256) void attn_kernel(
    const __bf16* __restrict__ QG, const __bf16* __restrict__ KV,
    const __bf16* __restrict__ eaC,
    const int* __restrict__ srcs, const int* __restrict__ offs,
    float* __restrict__ OUT, __bf16* __restrict__ AE) {
  __shared__ float sdn[4][64];
  __shared__ float sav[4][64][4], sae[4][64][4];
  const int lane = threadIdx.x & 63;
  const int w = threadIdx.x >> 6;
  const int n = blockIdx.x;
  const int sub = lane & 7;

  // fold 1/sqrt(32) * log2(e) into q,g once
  const float LSC = 0.25506589858f;
  const bf16x8 qg = *(const bf16x8*)(QG + (size_t)n * 512 + lane * 8);
  const float q0 = bf2f(qg[0]) * LSC, q1 = bf2f(qg[1]) * LSC;
  const float q2 = bf2f(qg[2]) * LSC, q3 = bf2f(qg[3]) * LSC;
  const float g0 = bf2f(qg[4]) * LSC, g1 = bf2f(qg[5]) * LSC;
  const float g2 = bf2f(qg[6]) * LSC, g3 = bf2f(qg[7]) * LSC;

  float denom = 0.f;
  float4v accv = {0.f, 0.f, 0.f, 0.f};
  float4v acce = {0.f, 0.f, 0.f, 0.f};
  const int beg = offs[n], end = offs[n + 1];

  int i = beg + w;
  for (; i + 4 < end; i += 8) {  // pair: edges i and i+4
    const int s0 = srcs[i];
    const int s1 = srcs[i + 4];
    const bf16x8 kv0 = *(const bf16x8*)(KV + (size_t)s0 * 512 + lane * 8);
    const bf16x4 a0 = *(const bf16x4*)(eaC + (size_t)i * 32 + sub * 4);
    const bf16x8 kv1 = *(const bf16x8*)(KV + (size_t)s1 * 512 + lane * 8);
    const bf16x4 a1 = *(const bf16x4*)(eaC + (size_t)(i + 4) * 32 + sub * 4);
    const float e00 = bf2f(a0[0]), e01 = bf2f(a0[1]), e02 = bf2f(a0[2]), e03 = bf2f(a0[3]);
    const float e10 = bf2f(a1[0]), e11 = bf2f(a1[1]), e12 = bf2f(a1[2]), e13 = bf2f(a1[3]);
    float p0 = q0 * bf2f(kv0[0]) + q1 * bf2f(kv0[1]) + q2 * bf2f(kv0[2]) + q3 * bf2f(kv0[3])
             + g0 * e00 + g1 * e01 + g2 * e02 + g3 * e03;
    float p1 = q0 * bf2f(kv1[0]) + q1 * bf2f(kv1[1]) + q2 * bf2f(kv1[2]) + q3 * bf2f(kv1[3])
             + g0 * e10 + g1 * e11 + g2 * e12 + g3 * e13;
    p0 += __shfl_xor(p0, 1); p1 += __shfl_xor(p1, 1);
    p0 += __shfl_xor(p0, 2); p1 += __shfl_xor(p1, 2);
    p0 += __shfl_xor(p0, 4); p1 += __shfl_xor(p1, 4);
    const float w0 = exp2f(p0);
    const float w1 = exp2f(p1);
    denom += w0 + w1;
    accv[0] += w0 * bf2f(kv0[4]) + w1 * bf2f(kv1[4]);
    accv[1] += w0 * bf2f(kv0[5]) + w1 * bf2f(kv1[5]);
    accv[2] += w0 * bf2f(kv0[6]) + w1 * bf2f(kv1[6]);
    accv[3] += w0 * bf2f(kv0[7]) + w1 * bf2f(kv1[7]);
    acce[0] += w0 * e00 + w1 * e10;
    acce[1] += w0 * e01 + w1 * e11;
    acce[2] += w0 * e02 + w1 * e12;
    acce[3] += w0 * e03 + w1 * e13;
  }
  if (i < end) {
    const int s0 = srcs[i];
    const bf16x8 kv0 = *(const bf16x8*)(KV + (size_t)s0 * 512 + lane * 8);
    const bf16x4 a0 = *(const bf16x4*)(eaC + (size_t)i * 32 + sub * 4);
    const float e00 = bf2f(a0[0]), e01 = bf2f(a0[1]), e02 = bf2f(a0[2]), e03 = bf2f(a0[3]);
    float p0 = q0 * bf2f(kv0[0]) + q1 * bf2f(kv0[1]) + q2 * bf2f(kv0[2]) + q3 * bf2f(kv0[3])
             + g0 * e00 + g1 * e01 + g2 * e02 + g3 * e03;
    p0 += __shfl_xor(p0, 1);
    p0 += __shfl_xor(p0, 2);
    p0 += __shfl_xor(p0, 4);
    const float w0 = exp2f(p0);
    denom += w0;
    accv[0] += w0 * bf2f(kv0[4]);
    accv[1] += w0 * bf2f(kv0[5]);
    accv[2] += w0 * bf2f(kv0[6]);
    accv[3] += w0 * bf2f(kv0[7]);
    acce[0] += w0 * e00;
    acce[1] += w0 * e01;
    acce[2] += w0 * e02;
    acce[3] += w0 * e03;
  }

  sdn[w][lane] = denom;
#pragma unroll
  for (int j = 0; j < 4; ++j) { sav[w][lane][j] = accv[j]; sae[w][lane][j] = acce[j]; }
  __syncthreads();
  if (w == 0) {
    float D = 0.f;
    float4v av = {0.f, 0.f, 0.f, 0.f};
    float4v ae = {0.f, 0.f, 0.f, 0.f};
#pragma unroll
    for (int ww = 0; ww < 4; ++ww) {
      D += sdn[ww][lane];
#pragma unroll
      for (int j = 0; j < 4; ++j) { av[j] += sav[ww][lane][j]; ae[j] += sae[ww][lane][j]; }
    }
    const float inv = 1.0f / (D + 1e-16f);
    const int c0 = lane * 4;
    float4v o = *(const float4v*)(OUT + (size_t)n * 256 + c0);
#pragma unroll
    for (int j = 0; j < 4; ++j) o[j] += av[j] * inv;
    *(float4v*)(OUT + (size_t)n * 256 + c0) = o;
    bf16x4 aeb;
    aeb[0] = f2bf(ae[0] * inv); aeb[1] = f2bf(ae[1] * inv);
    aeb[2] = f2bf(ae[2] * inv); aeb[3] = f2bf(ae[3] * inv);
    *(bf16x4*)(AE + (size_t)n * 256 + c0) = aeb;
  }
}

// ---------------- post: OUT += AE@We (per-head); OUTh = bf16(OUT) ----------------
__global__ __launch_bounds__(256) void post_kernel(
    const __bf16* __restrict__ AE, const float* __restrict__ WeT,
    float* __restrict__ OUT, __bf16* __restrict__ OUTh) {
  const int lane = threadIdx.x & 63;
  const int wave = threadIdx.x >> 6;
  const int c0 = lane * 4;
  const int hg = lane >> 3;

  float4v w4[4][8];
#pragma unroll
  for (int j = 0; j < 4; ++j)
#pragma unroll
    for (int s = 0; s < 8; ++s)
      w4[j][s] = *(const float4v*)(WeT + (size_t)(c0 + j) * 32 + s * 4);

  const int nbase = blockIdx.x * 64;
  for (int it = 0; it < 16; ++it) {
    const int n = nbase + it * 4 + wave;
    if (n >= NN) return;
    const __bf16* aerow = AE + (size_t)n * HIDDEN + hg * 32;
    float aef[32];
#pragma unroll
    for (int t = 0; t < 4; ++t) {
      bf16x8 a8 = *(const bf16x8*)(aerow + t * 8);
#pragma unroll
      for (int j = 0; j < 8; ++j) aef[t * 8 + j] = bf2f(a8[j]);
    }
    float4v o = *(const float4v*)(OUT + (size_t)n * HIDDEN + c0);
#pragma unroll
    for (int j = 0; j < 4; ++j) {
      float s = 0.f;
#pragma unroll
      for (int g = 0; g < 8; ++g) {
        s += aef[g * 4 + 0] * w4[j][g][0] + aef[g * 4 + 1] * w4[j][g][1]
           + aef[g * 4 + 2] * w4[j][g][2] + aef[g * 4 + 3] * w4[j][g][3];
      }
      o[j] += s;
    }
    *(float4v*)(OUT + (size_t)n * HIDDEN + c0) = o;
    bf16x4 ob;
    ob[0] = f2bf(o[0]); ob[1] = f2bf(o[1]); ob[2] = f2bf(o[2]); ob[3] = f2bf(o[3]);
    *(bf16x4*)(OUTh + (size_t)n * HIDDEN + c0) = ob;
  }
}

extern "C" void kernel_launch(void* const* d_in, const int* in_sizes, int n_in,
                              void* d_out, int out_size, void* d_ws, size_t ws_size,
                              hipStream_t stream) {
  (void)in_sizes; (void)n_in; (void)out_size; (void)ws_size;
  const float* x   = (const float*)d_in[0];
  const int*   ei  = (const int*)d_in[1];
  const float* ea  = (const float*)d_in[2];
  const float* Wq  = (const float*)d_in[3];
  const float* bq  = (const float*)d_in[4];
  const float* Wk  = (const float*)d_in[5];
  const float* bk  = (const float*)d_in[6];
  const float* Wv  = (const float*)d_in[7];
  const float* bv  = (const float*)d_in[8];
  const float* We  = (const float*)d_in[9];
  const float* Wsk = (const float*)d_in[10];
  const float* W1  = (const float*)d_in[11];
  const float* b1  = (const float*)d_in[12];
  const float* W2  = (const float*)d_in[13];
  const float* b2  = (const float*)d_in[14];
  float* out = (float*)d_out;

  char* ws = (char*)d_ws;
  size_t off = 0;
  auto alloc = [&](size_t bytes) -> char* {
    off = (off + 255) & ~(size_t)255;
    char* p = ws + off;
    off += bytes;
    return p;
  };
  __bf16* QG   = (__bf16*)alloc((size_t)NN * 512 * 2);
  __bf16* KV   = (__bf16*)alloc((size_t)NN * 512 * 2);
  __bf16* xb   = (__bf16*)alloc((size_t)NN * 256 * 2);
  __bf16* AE   = (__bf16*)alloc((size_t)NN * 256 * 2);      // reused as H1
  __bf16* OUTh = (__bf16*)alloc((size_t)NN * 256 * 2);
  __bf16* eaC  = (__bf16*)alloc((size_t)NE * 32 * 2);
  __bf16* WTall = (__bf16*)alloc((size_t)1280 * 256 * 2);
  __bf16* WT1  = (__bf16*)alloc(256 * 256 * 2);
  __bf16* WT2  = (__bf16*)alloc(256 * 256 * 2);
  float*  ball = (float*)alloc(1280 * 4);
  float*  WeT  = (float*)alloc(256 * 32 * 4);
  int* deg    = (int*)alloc((size_t)2 * NN * 4);
  int* cursor = deg + NN;
  int* offs   = (int*)alloc((size_t)(NN + 1) * 4);
  int* srcs   = (int*)alloc((size_t)NE * 4);
  __bf16* H1 = AE;

  const int* srcIn = ei;       // edge_index[0]
  const int* dstIn = ei + NE;  // edge_index[1]

  // ---- fused prep (weights + x->bf16 + zero deg/cursor) ----
  const int prepBlocks = PREP_XB_END + (2 * NN + 255) / 256;
  prep_kernel<<<prepBlocks, 256, 0, stream>>>(Wq, Wk, Wv, Wsk, W1, W2, We, bq, bk, bv, x,
                                              WTall, WT1, WT2, ball, WeT, xb, deg);

  // ---- CSR build (count -> fused offs -> scatter+ea permute) ----
  const int nb = (NN + 255) / 256;  // 118
  count_deg_kernel<<<(NE + 255) / 256, 256, 0, stream>>>(dstIn, deg, NE);
  offs_fused_kernel<<<nb, 256, 0, stream>>>(deg, offs, NN);
  scatter_kernel<<<(NE + 255) / 256, 256, 0, stream>>>(srcIn, dstIn, ea, offs, cursor,
                                                       srcs, eaC, NE);

  const int gy = (NN + 127) / 128;          // 235
  const int stripes = (gy + 7) / 8;         // 30
  // ---- fused node GEMM: Q|K|V|QE -> QG/KV interleaved, skip -> out (fp32) ----
  // TN=64: 4 blocks/CU (was 2), 4800 blocks
  gemm_k4<10, 0, 1, 64><<<stripes * 160, 256, 0, stream>>>(
      xb, WTall, ball, out, nullptr, QG, KV, nullptr, NN, gy);

  // ---- attention (RMW out, write AE): v5 structure, wave-0 epilogue ----
  attn_kernel<<<NN, 256, 0, stream>>>(QG, KV, eaC, srcs, offs, out, AE);

  // ---- post: out += AE @ We (per-head), OUTh = bf16(out) ----
  post_kernel<<<(NN + 63) / 64, 256, 0, stream>>>(AE, WeT, out, OUTh);

  // ---- MLP (TN=32: 8 blocks/CU, 1920 blocks) ----
  gemm_k4<2, 2, 0, 32><<<stripes * 64, 256, 0, stream>>>(
      OUTh, WT1, b1, nullptr, H1, nullptr, nullptr, nullptr, NN, gy);
  gemm_k4<2, 3, 0, 32><<<stripes * 64, 256, 0, stream>>>(
      H1, WT2, b2, out, nullptr, nullptr, nullptr, out, NN, gy);
}

// Round 13
// 362.680 us; speedup vs baseline: 1.0183x; 1.0183x over previous
//
#include <hip/hip_runtime.h>

#define NN 30000
#define NE 300000
#define HIDDEN 256

typedef __attribute__((ext_vector_type(8))) __bf16 bf16x8;
typedef __attribute__((ext_vector_type(4))) __bf16 bf16x4;
typedef __attribute__((ext_vector_type(4))) float float4v;

__device__ inline __bf16 f2bf(float f) {
  unsigned u = __builtin_bit_cast(unsigned, f);
  u += 0x7fffu + ((u >> 16) & 1u);
  unsigned short s = (unsigned short)(u >> 16);
  return __builtin_bit_cast(__bf16, s);
}
__device__ inline float bf2f(__bf16 b) {
  unsigned short s = __builtin_bit_cast(unsigned short, b);
  unsigned u = ((unsigned)s) << 16;
  return __builtin_bit_cast(float, u);
}
__device__ inline float gelu_tanh(float x) {
  float x3 = x * x * x;
  return 0.5f * x * (1.0f + tanhf(0.79788456080286536f * (x + 0.044715f * x3)));
}

// ---------------- fused prep: 7 weight transposes + ball + WeT + x->bf16 + zero ints --------
#define PREP_XB_END (1829 + (NN * 32 + 255) / 256)
__global__ __launch_bounds__(256) void prep_kernel(
    const float* __restrict__ Wq, const float* __restrict__ Wk, const float* __restrict__ Wv,
    const float* __restrict__ Wsk, const float* __restrict__ W1, const float* __restrict__ W2,
    const float* __restrict__ We, const float* __restrict__ bq, const float* __restrict__ bk,
    const float* __restrict__ bv, const float* __restrict__ x,
    __bf16* __restrict__ WTall, __bf16* __restrict__ WT1, __bf16* __restrict__ WT2,
    float* __restrict__ ball, float* __restrict__ WeT, __bf16* __restrict__ xb,
    int* __restrict__ degz) {
  const int b = blockIdx.x;
  const int tid = threadIdx.x;
  if (b < 1792) {
    const int region = b >> 8;
    const int idx = ((b & 255) << 8) | tid;  // [n(8b)|k(8b)] -> Wt[n][k]
    const int k = idx & 255, n = idx >> 8;
    float v;
    if (region == 3) {  // Wqe[k][n] on the fly: n = h*32+d
      const int h = n >> 5, d = n & 31;
      const float* wq = Wq + (size_t)k * 256 + h * 32;
      const float* we = We + (size_t)d * 256 + h * 32;
      float s = 0.f;
#pragma unroll
      for (int c = 0; c < 32; ++c) s += wq[c] * we[c];
      v = s;
    } else {
      const float* W = (region == 0) ? Wq : (region == 1) ? Wk : (region == 2) ? Wv
                     : (region == 4) ? Wsk : (region == 5) ? W1 : W2;
      v = W[(size_t)k * 256 + n];
    }
    const __bf16 bv16 = f2bf(v);
    if (region < 5) WTall[(size_t)region * 65536 + idx] = bv16;
    else if (region == 5) WT1[idx] = bv16;
    else WT2[idx] = bv16;
  } else if (b < 1797) {
    const int j = (b - 1792) * 256 + tid;
    if (j < 1280) {
      float v = 0.f;
      if (j < 256) v = bq[j];
      else if (j < 512) v = bk[j - 256];
      else if (j < 768) v = bv[j - 512];
      else if (j < 1024) {
        const int col = j - 768, h = col >> 5, d = col & 31;
        const float* bqh = bq + h * 32;
        const float* we = We + (size_t)d * 256 + h * 32;
        float s = 0.f;
#pragma unroll
        for (int c = 0; c < 32; ++c) s += bqh[c] * we[c];
        v = s;
      }
      ball[j] = v;
    }
  } else if (b < 1829) {
    const int idx = (b - 1797) * 256 + tid;  // < 8192
    const int ch = idx >> 5, d = idx & 31;
    WeT[idx] = We[(size_t)d * 256 + ch];
  } else if (b < PREP_XB_END) {
    const int t = (b - 1829) * 256 + tid;
    if (t < NN * 256 / 8) {
      const float* p = x + (size_t)t * 8;
      float4v f0 = *(const float4v*)(p);
      float4v f1 = *(const float4v*)(p + 4);
      bf16x8 o;
#pragma unroll
      for (int j = 0; j < 4; ++j) { o[j] = f2bf(f0[j]); o[j + 4] = f2bf(f1[j]); }
      *(bf16x8*)(xb + (size_t)t * 8) = o;
    }
  } else {
    const int idx = (b - PREP_XB_END) * 256 + tid;
    if (idx < 2 * NN) degz[idx] = 0;
  }
}

// ---------------- CSR build ----------------
__global__ void count_deg_kernel(const int* __restrict__ dst, int* __restrict__ deg, int E) {
  int e = blockIdx.x * 256 + threadIdx.x;
  if (e < E) atomicAdd(&deg[dst[e]], 1);
}

// fused offs: block computes its exclusive base by redundant sum of deg[0..blk*256)
// then intra-block scan. 1 kernel replaces psum+scan+offs; no cross-block sync.
__global__ __launch_bounds__(256) void offs_fused_kernel(const int* __restrict__ deg,
                                                         int* __restrict__ offs, int n) {
  __shared__ int tmp[256];
  __shared__ int sbase[4];
  const int t = threadIdx.x;
  const int lim = blockIdx.x * 256;
  int bp = 0;
  for (int idx = t; idx < lim; idx += 256) bp += deg[idx];
#pragma unroll
  for (int s = 1; s < 64; s <<= 1) bp += __shfl_xor(bp, s);
  if ((t & 63) == 0) sbase[t >> 6] = bp;
  const int i = lim + t;
  int v = (i < n) ? deg[i] : 0;
  tmp[t] = v;
  __syncthreads();
  const int base = sbase[0] + sbase[1] + sbase[2] + sbase[3];
  for (int s = 1; s < 256; s <<= 1) {
    int u = (t >= s) ? tmp[t - s] : 0;
    __syncthreads();
    tmp[t] += u;
    __syncthreads();
  }
  if (i < n) offs[i] = base + tmp[t] - v;
  if (blockIdx.x == gridDim.x - 1 && t == 0) offs[n] = NE;
}

// scatter + fused ea permute: coalesced fp32 ea read (e sequential), bf16
// convert, scattered 64B write to CSR slot (random WRITES are fire-and-forget).
__global__ void scatter_kernel(const int* __restrict__ srcIn, const int* __restrict__ dstIn,
                               const float* __restrict__ ea,
                               const int* __restrict__ offs, int* __restrict__ cursor,
                               int* __restrict__ srcs, __bf16* __restrict__ eaC, int E) {
  int e = blockIdx.x * 256 + threadIdx.x;
  if (e >= E) return;
  const float* src = ea + (size_t)e * 32;
  float4v f[8];
#pragma unroll
  for (int t = 0; t < 8; ++t) f[t] = *(const float4v*)(src + t * 4);
  int d = dstIn[e];
  int p = atomicAdd(&cursor[d], 1);
  int o = offs[d] + p;
  srcs[o] = srcIn[e];
  __bf16* dstp = eaC + (size_t)o * 32;
#pragma unroll
  for (int t = 0; t < 4; ++t) {
    bf16x8 b;
#pragma unroll
    for (int j = 0; j < 4; ++j) { b[j] = f2bf(f[t * 2][j]); b[j + 4] = f2bf(f[t * 2 + 1][j]); }
    *(bf16x8*)(dstp + t * 8) = b;
  }
}

// ---------------- MFMA GEMM v5: tileable N (TN) for occupancy ---------------
// TN=128: B-tile 67.6KB, 2 blocks/CU. TN=64: 34.8KB, 4 blocks/CU (verified
// lever on MLP: 66us@128 -> <61@64). TN=32 regressed (R12: MFMA density).
template <int GX, int EPI, int MODE, int TN>
__global__ __launch_bounds__(256) void gemm_k4(
    const __bf16* __restrict__ A, const __bf16* __restrict__ Wt,
    const float* __restrict__ bias,
    float* __restrict__ Yf, __bf16* __restrict__ Ybf,
    __bf16* __restrict__ QGp, __bf16* __restrict__ KVp,
    const float* __restrict__ resid, int M, int gyTiles) {
  constexpr int XT = (GX * 128) / TN;   // col-tiles
  constexpr int NT = TN / 16;           // MFMA col frags per wave
  constexpr int CST = TN + 4;           // C-stage stride (floats)
  constexpr size_t SM_B = (size_t)TN * 264 * 2;
  constexpr size_t SM_C = (size_t)4 * 32 * CST * 4;
  constexpr size_t SMEM = SM_B > SM_C ? SM_B : SM_C;
  __shared__ __attribute__((aligned(16))) char smem[SMEM];
  __bf16* Bs = (__bf16*)smem;
  const int bid = blockIdx.x;
  const int stripe = bid / (8 * XT);
  const int rem = bid % (8 * XT);
  const int y8 = rem % 8;   // XCD id: col-blocks of one row-stripe share an XCD
  const int xt = rem / 8;
  const int y = stripe * 8 + y8;
  if (y >= gyTiles) return;
  const int n0 = xt * TN;

  {
    const int t = threadIdx.x;
#pragma unroll
    for (int i = 0; i < TN / 8; ++i) {  // TN*32 chunks / 256 threads
      int g = i * 256 + t;
      int row = g >> 5;
      int c16 = g & 31;
      bf16x8 v = *(const bf16x8*)(Wt + (size_t)(n0 + row) * 256 + c16 * 8);
      *(bf16x8*)(Bs + row * 264 + c16 * 8) = v;
    }
  }
  __syncthreads();

  const int lane = threadIdx.x & 63;
  const int w = threadIdx.x >> 6;
  const int r = lane & 15;
  const int q = lane >> 4;
  const int mw = y * 128 + w * 32;
  int ar0 = mw + r;      if (ar0 >= M) ar0 = M - 1;
  int ar1 = mw + 16 + r; if (ar1 >= M) ar1 = M - 1;
  const int kq = q * 8;

  float4v acc[2][NT];
#pragma unroll
  for (int i = 0; i < 2; ++i)
#pragma unroll
    for (int t = 0; t < NT; ++t) acc[i][t] = (float4v){0.f, 0.f, 0.f, 0.f};

#pragma unroll
  for (int kk = 0; kk < 256; kk += 32) {
    const int ka = kk + kq;
    bf16x8 a0 = *(const bf16x8*)(A + (size_t)ar0 * 256 + ka);
    bf16x8 a1 = *(const bf16x8*)(A + (size_t)ar1 * 256 + ka);
    bf16x8 b[NT];
#pragma unroll
    for (int t = 0; t < NT; ++t)
      b[t] = *(const bf16x8*)(Bs + (t * 16 + r) * 264 + ka);
#pragma unroll
    for (int t = 0; t < NT; ++t) {
      acc[0][t] = __builtin_amdgcn_mfma_f32_16x16x32_bf16(a0, b[t], acc[0][t], 0, 0, 0);
      acc[1][t] = __builtin_amdgcn_mfma_f32_16x16x32_bf16(a1, b[t], acc[1][t], 0, 0, 0);
    }
  }
  __syncthreads();  // B-tile dead; reuse LDS as C-stage

  // stage C (fp32, stride CST) with bias/gelu applied
  float* cs = (float*)smem + w * 32 * CST;
#pragma unroll
  for (int t = 0; t < NT; ++t) {
    const int col = n0 + t * 16 + r;
    const float bb = bias ? bias[col] : 0.0f;
#pragma unroll
    for (int i2 = 0; i2 < 2; ++i2)
#pragma unroll
      for (int ii = 0; ii < 4; ++ii) {
        float v = acc[i2][t][ii] + bb;
        if constexpr (EPI == 2 || EPI == 3) v = gelu_tanh(v);
        cs[(i2 * 16 + q * 4 + ii) * CST + t * 16 + r] = v;
      }
  }

  // coalesced read-back + vector stores (per-wave region; same-wave LDS order ok)
  constexpr int NSTR = GX * 128;
  constexpr int RPI = 256 / TN;   // rows per iter
  constexpr int LPR = TN / 4;     // lanes per row
  const int p = n0 >> 8;
  const int cbase = n0 & 255;
  __bf16* dstI = (p == 0 || p == 3) ? QGp : KVp;
  const int moff = (p >= 2) ? 4 : 0;  // planes 2(V),3(G) are second member
#pragma unroll
  for (int i = 0; i < 32 / RPI; ++i) {
    const int rl = i * RPI + lane / LPR;
    const int row = mw + rl;
    const int c4 = (lane % LPR) * 4;
    float4v v = *(const float4v*)(cs + rl * CST + c4);
    if (row < M) {
      if constexpr (MODE == 1) {
        if (p == 4) {
          *(float4v*)(Yf + (size_t)row * 256 + cbase + c4) = v;
        } else {
          bf16x4 b4;
          b4[0] = f2bf(v[0]); b4[1] = f2bf(v[1]); b4[2] = f2bf(v[2]); b4[3] = f2bf(v[3]);
          const int c = cbase + c4;
          *(bf16x4*)(dstI + (size_t)row * 512 + 2 * c + moff) = b4;
        }
      } else if constexpr (EPI == 1) {
        *(float4v*)(Yf + (size_t)row * NSTR + n0 + c4) = v;
      } else if constexpr (EPI == 3) {
        float4v rr = *(const float4v*)(resid + (size_t)row * NSTR + n0 + c4);
        v[0] += rr[0]; v[1] += rr[1]; v[2] += rr[2]; v[3] += rr[3];
        *(float4v*)(Yf + (size_t)row * NSTR + n0 + c4) = v;
      } else {  // bf16 out
        bf16x4 b4;
        b4[0] = f2bf(v[0]); b4[1] = f2bf(v[1]); b4[2] = f2bf(v[2]); b4[3] = f2bf(v[3]);
        *(bf16x4*)(Ybf + (size_t)row * NSTR + n0 + c4) = b4;
      }
    }
  }
}

// ---------------- attention (v5 exact, proven 61us): 4 waves/node, direct
// per-edge srcs loads, 2-edge unroll (i, i+4), single random-gather stream
// (KV); eaC CSR-ordered sequential; exp2 with prefolded scale; wave-0 epilogue.
__global__ __launch_bounds__(256) void attn_kernel(
    const __bf16* __restrict__ QG, const __bf16* __restrict__ KV,
    const __bf16* __restrict__ eaC,
    const int* __restrict__ srcs, const int* __restrict__ offs,
    float* __restrict__ OUT, __bf16* __restrict__ AE) {
  __shared__ float sdn[4][64];
  __shared__ float sav[4][64][4], sae[4][64][4];
  const int lane = threadIdx.x & 63;
  const int w = threadIdx.x >> 6;
  const int n = blockIdx.x;
  const int sub = lane & 7;

  // fold 1/sqrt(32) * log2(e) into q,g once
  const float LSC = 0.25506589858f;
  const bf16x8 qg = *(const bf16x8*)(QG + (size_t)n * 512 + lane * 8);
  const float q0 = bf2f(qg[0]) * LSC, q1 = bf2f(qg[1]) * LSC;
  const float q2 = bf2f(qg[2]) * LSC, q3 = bf2f(qg[3]) * LSC;
  const float g0 = bf2f(qg[4]) * LSC, g1 = bf2f(qg[5]) * LSC;
  const float g2 = bf2f(qg[6]) * LSC, g3 = bf2f(qg[7]) * LSC;

  float denom = 0.f;
  float4v accv = {0.f, 0.f, 0.f, 0.f};
  float4v acce = {0.f, 0.f, 0.f, 0.f};
  const int beg = offs[n], end = offs[n + 1];

  int i = beg + w;
  for (; i + 4 < end; i += 8) {  // pair: edges i and i+4
    const int s0 = srcs[i];
    const int s1 = srcs[i + 4];
    const bf16x8 kv0 = *(const bf16x8*)(KV + (size_t)s0 * 512 + lane * 8);
    const bf16x4 a0 = *(const bf16x4*)(eaC + (size_t)i * 32 + sub * 4);
    const bf16x8 kv1 = *(const bf16x8*)(KV + (size_t)s1 * 512 + lane * 8);
    const bf16x4 a1 = *(const bf16x4*)(eaC + (size_t)(i + 4) * 32 + sub * 4);
    const float e00 = bf2f(a0[0]), e01 = bf2f(a0[1]), e02 = bf2f(a0[2]), e03 = bf2f(a0[3]);
    const float e10 = bf2f(a1[0]), e11 = bf2f(a1[1]), e12 = bf2f(a1[2]), e13 = bf2f(a1[3]);
    float p0 = q0 * bf2f(kv0[0]) + q1 * bf2f(kv0[1]) + q2 * bf2f(kv0[2]) + q3 * bf2f(kv0[3])
             + g0 * e00 + g1 * e01 + g2 * e02 + g3 * e03;
    float p1 = q0 * bf2f(kv1[0]) + q1 * bf2f(kv1[1]) + q2 * bf2f(kv1[2]) + q3 * bf2f(kv1[3])
             + g0 * e10 + g1 * e11 + g2 * e12 + g3 * e13;
    p0 += __shfl_xor(p0, 1); p1 += __shfl_xor(p1, 1);
    p0 += __shfl_xor(p0, 2); p1 += __shfl_xor(p1, 2);
    p0 += __shfl_xor(p0, 4); p1 += __shfl_xor(p1, 4);
    const float w0 = exp2f(p0);
    const float w1 = exp2f(p1);
    denom += w0 + w1;
    accv[0] += w0 * bf2f(kv0[4]) + w1 * bf2f(kv1[4]);
    accv[1] += w0 * bf2f(kv0[5]) + w1 * bf2f(kv1[5]);
    accv[2] += w0 * bf2f(kv0[6]) + w1 * bf2f(kv1[6]);
    accv[3] += w0 * bf2f(kv0[7]) + w1 * bf2f(kv1[7]);
    acce[0] += w0 * e00 + w1 * e10;
    acce[1] += w0 * e01 + w1 * e11;
    acce[2] += w0 * e02 + w1 * e12;
    acce[3] += w0 * e03 + w1 * e13;
  }
  if (i < end) {
    const int s0 = srcs[i];
    const bf16x8 kv0 = *(const bf16x8*)(KV + (size_t)s0 * 512 + lane * 8);
    const bf16x4 a0 = *(const bf16x4*)(eaC + (size_t)i * 32 + sub * 4);
    const float e00 = bf2f(a0[0]), e01 = bf2f(a0[1]), e02 = bf2f(a0[2]), e03 = bf2f(a0[3]);
    float p0 = q0 * bf2f(kv0[0]) + q1 * bf2f(kv0[1]) + q2 * bf2f(kv0[2]) + q3 * bf2f(kv0[3])
             + g0 * e00 + g1 * e01 + g2 * e02 + g3 * e03;
    p0 += __shfl_xor(p0, 1);
    p0 += __shfl_xor(p0, 2);
    p0 += __shfl_xor(p0, 4);
    const float w0 = exp2f(p0);
    denom += w0;
    accv[0] += w0 * bf2f(kv0[4]);
    accv[1] += w0 * bf2f(kv0[5]);
    accv[2] += w0 * bf2f(kv0[6]);
    accv[3] += w0 * bf2f(kv0[7]);
    acce[0] += w0 * e00;
    acce[1] += w0 * e01;
    acce[2] += w0 * e02;
    acce[3] += w0 * e03;
  }

  sdn[w][lane] = denom;
#pragma unroll
  for (int j = 0; j < 4; ++j) { sav[w][lane][j] = accv[j]; sae[w][lane][j] = acce[j]; }
  __syncthreads();
  if (w == 0) {
    float D = 0.f;
    float4v av = {0.f, 0.f, 0.f, 0.f};
    float4v ae = {0.f, 0.f, 0.f, 0.f};
#pragma unroll
    for (int ww = 0; ww < 4; ++ww) {
      D += sdn[ww][lane];
#pragma unroll
      for (int j = 0; j < 4; ++j) { av[j] += sav[ww][lane][j]; ae[j] += sae[ww][lane][j]; }
    }
    const float inv = 1.0f / (D + 1e-16f);
    const int c0 = lane * 4;
    float4v o = *(const float4v*)(OUT + (size_t)n * 256 + c0);
#pragma unroll
    for (int j = 0; j < 4; ++j) o[j] += av[j] * inv;
    *(float4v*)(OUT + (size_t)n * 256 + c0) = o;
    bf16x4 aeb;
    aeb[0] = f2bf(ae[0] * inv); aeb[1] = f2bf(ae[1] * inv);
    aeb[2] = f2bf(ae[2] * inv); aeb[3] = f2bf(ae[3] * inv);
    *(bf16x4*)(AE + (size_t)n * 256 + c0) = aeb;
  }
}

// ---------------- post: OUT += AE@We (per-head); OUTh = bf16(OUT) ----------------
__global__ __launch_bounds__(256) void post_kernel(
    const __bf16* __restrict__ AE, const float* __restrict__ WeT,
    float* __restrict__ OUT, __bf16* __restrict__ OUTh) {
  const int lane = threadIdx.x & 63;
  const int wave = threadIdx.x >> 6;
  const int c0 = lane * 4;
  const int hg = lane >> 3;

  float4v w4[4][8];
#pragma unroll
  for (int j = 0; j < 4; ++j)
#pragma unroll
    for (int s = 0; s < 8; ++s)
      w4[j][s] = *(const float4v*)(WeT + (size_t)(c0 + j) * 32 + s * 4);

  const int nbase = blockIdx.x * 64;
  for (int it = 0; it < 16; ++it) {
    const int n = nbase + it * 4 + wave;
    if (n >= NN) return;
    const __bf16* aerow = AE + (size_t)n * HIDDEN + hg * 32;
    float aef[32];
#pragma unroll
    for (int t = 0; t < 4; ++t) {
      bf16x8 a8 = *(const bf16x8*)(aerow + t * 8);
#pragma unroll
      for (int j = 0; j < 8; ++j) aef[t * 8 + j] = bf2f(a8[j]);
    }
    float4v o = *(const float4v*)(OUT + (size_t)n * HIDDEN + c0);
#pragma unroll
    for (int j = 0; j < 4; ++j) {
      float s = 0.f;
#pragma unroll
      for (int g = 0; g < 8; ++g) {
        s += aef[g * 4 + 0] * w4[j][g][0] + aef[g * 4 + 1] * w4[j][g][1]
           + aef[g * 4 + 2] * w4[j][g][2] + aef[g * 4 + 3] * w4[j][g][3];
      }
      o[j] += s;
    }
    *(float4v*)(OUT + (size_t)n * HIDDEN + c0) = o;
    bf16x4 ob;
    ob[0] = f2bf(o[0]); ob[1] = f2bf(o[1]); ob[2] = f2bf(o[2]); ob[3] = f2bf(o[3]);
    *(bf16x4*)(OUTh + (size_t)n * HIDDEN + c0) = ob;
  }
}

extern "C" void kernel_launch(void* const* d_in, const int* in_sizes, int n_in,
                              void* d_out, int out_size, void* d_ws, size_t ws_size,
                              hipStream_t stream) {
  (void)in_sizes; (void)n_in; (void)out_size; (void)ws_size;
  const float* x   = (const float*)d_in[0];
  const int*   ei  = (const int*)d_in[1];
  const float* ea  = (const float*)d_in[2];
  const float* Wq  = (const float*)d_in[3];
  const float* bq  = (const float*)d_in[4];
  const float* Wk  = (const float*)d_in[5];
  const float* bk  = (const float*)d_in[6];
  const float* Wv  = (const float*)d_in[7];
  const float* bv  = (const float*)d_in[8];
  const float* We  = (const float*)d_in[9];
  const float* Wsk = (const float*)d_in[10];
  const float* W1  = (const float*)d_in[11];
  const float* b1  = (const float*)d_in[12];
  const float* W2  = (const float*)d_in[13];
  const float* b2  = (const float*)d_in[14];
  float* out = (float*)d_out;

  char* ws = (char*)d_ws;
  size_t off = 0;
  auto alloc = [&](size_t bytes) -> char* {
    off = (off + 255) & ~(size_t)255;
    char* p = ws + off;
    off += bytes;
    return p;
  };
  __bf16* QG   = (__bf16*)alloc((size_t)NN * 512 * 2);
  __bf16* KV   = (__bf16*)alloc((size_t)NN * 512 * 2);
  __bf16* xb   = (__bf16*)alloc((size_t)NN * 256 * 2);
  __bf16* AE   = (__bf16*)alloc((size_t)NN * 256 * 2);      // reused as H1
  __bf16* OUTh = (__bf16*)alloc((size_t)NN * 256 * 2);
  __bf16* eaC  = (__bf16*)alloc((size_t)NE * 32 * 2);
  __bf16* WTall = (__bf16*)alloc((size_t)1280 * 256 * 2);
  __bf16* WT1  = (__bf16*)alloc(256 * 256 * 2);
  __bf16* WT2  = (__bf16*)alloc(256 * 256 * 2);
  float*  ball = (float*)alloc(1280 * 4);
  float*  WeT  = (float*)alloc(256 * 32 * 4);
  int* deg    = (int*)alloc((size_t)2 * NN * 4);
  int* cursor = deg + NN;
  int* offs   = (int*)alloc((size_t)(NN + 1) * 4);
  int* srcs   = (int*)alloc((size_t)NE * 4);
  __bf16* H1 = AE;

  const int* srcIn = ei;       // edge_index[0]
  const int* dstIn = ei + NE;  // edge_index[1]

  // ---- fused prep (weights + x->bf16 + zero deg/cursor) ----
  const int prepBlocks = PREP_XB_END + (2 * NN + 255) / 256;
  prep_kernel<<<prepBlocks, 256, 0, stream>>>(Wq, Wk, Wv, Wsk, W1, W2, We, bq, bk, bv, x,
                                              WTall, WT1, WT2, ball, WeT, xb, deg);

  // ---- CSR build (count -> fused offs -> scatter+ea permute) ----
  const int nb = (NN + 255) / 256;  // 118
  count_deg_kernel<<<(NE + 255) / 256, 256, 0, stream>>>(dstIn, deg, NE);
  offs_fused_kernel<<<nb, 256, 0, stream>>>(deg, offs, NN);
  scatter_kernel<<<(NE + 255) / 256, 256, 0, stream>>>(srcIn, dstIn, ea, offs, cursor,
                                                       srcs, eaC, NE);

  const int gy = (NN + 127) / 128;          // 235
  const int stripes = (gy + 7) / 8;         // 30
  // ---- fused node GEMM: Q|K|V|QE -> QG/KV interleaved, skip -> out (fp32) ----
  // ISOLATION EXPERIMENT (R12 was confounded): TN=64 here, MLP back at TN=64
  gemm_k4<10, 0, 1, 64><<<stripes * 160, 256, 0, stream>>>(
      xb, WTall, ball, out, nullptr, QG, KV, nullptr, NN, gy);

  // ---- attention (RMW out, write AE): v5 structure, wave-0 epilogue ----
  attn_kernel<<<NN, 256, 0, stream>>>(QG, KV, eaC, srcs, offs, out, AE);

  // ---- post: out += AE @ We (per-head), OUTh = bf16(out) ----
  post_kernel<<<(NN + 63) / 64, 256, 0, stream>>>(AE, WeT, out, OUTh);

  // ---- MLP (TN=64: proven best — R11) ----
  gemm_k4<2, 2, 0, 64><<<stripes * 32, 256, 0, stream>>>(
      OUTh, WT1, b1, nullptr, H1, nullptr, nullptr, nullptr, NN, gy);
  gemm_k4<2, 3, 0, 64><<<stripes * 32, 256, 0, stream>>>(
      H1, WT2, b2, out, nullptr, nullptr, nullptr, out, NN, gy);
}

// Round 14
// 357.795 us; speedup vs baseline: 1.0322x; 1.0137x over previous
//
#include <hip/hip_runtime.h>

#define NN 30000
#define NE 300000
#define HIDDEN 256

typedef __attribute__((ext_vector_type(8))) __bf16 bf16x8;
typedef __attribute__((ext_vector_type(4))) __bf16 bf16x4;
typedef __attribute__((ext_vector_type(4))) float float4v;

__device__ inline __bf16 f2bf(float f) {
  unsigned u = __builtin_bit_cast(unsigned, f);
  u += 0x7fffu + ((u >> 16) & 1u);
  unsigned short s = (unsigned short)(u >> 16);
  return __builtin_bit_cast(__bf16, s);
}
__device__ inline float bf2f(__bf16 b) {
  unsigned short s = __builtin_bit_cast(unsigned short, b);
  unsigned u = ((unsigned)s) << 16;
  return __builtin_bit_cast(float, u);
}
__device__ inline float gelu_tanh(float x) {
  float x3 = x * x * x;
  return 0.5f * x * (1.0f + tanhf(0.79788456080286536f * (x + 0.044715f * x3)));
}

// ---------------- fused prep: 7 weight transposes + ball + WeT + x->bf16 + zero ints --------
#define PREP_XB_END (1829 + (NN * 32 + 255) / 256)
__global__ __launch_bounds__(256) void prep_kernel(
    const float* __restrict__ Wq, const float* __restrict__ Wk, const float* __restrict__ Wv,
    const float* __restrict__ Wsk, const float* __restrict__ W1, const float* __restrict__ W2,
    const float* __restrict__ We, const float* __restrict__ bq, const float* __restrict__ bk,
    const float* __restrict__ bv, const float* __restrict__ x,
    __bf16* __restrict__ WTall, __bf16* __restrict__ WT1, __bf16* __restrict__ WT2,
    float* __restrict__ ball, float* __restrict__ WeT, __bf16* __restrict__ xb,
    int* __restrict__ degz) {
  const int b = blockIdx.x;
  const int tid = threadIdx.x;
  if (b < 1792) {
    const int region = b >> 8;
    const int idx = ((b & 255) << 8) | tid;  // [n(8b)|k(8b)] -> Wt[n][k]
    const int k = idx & 255, n = idx >> 8;
    float v;
    if (region == 3) {  // Wqe[k][n] on the fly: n = h*32+d
      const int h = n >> 5, d = n & 31;
      const float* wq = Wq + (size_t)k * 256 + h * 32;
      const float* we = We + (size_t)d * 256 + h * 32;
      float s = 0.f;
#pragma unroll
      for (int c = 0; c < 32; ++c) s += wq[c] * we[c];
      v = s;
    } else {
      const float* W = (region == 0) ? Wq : (region == 1) ? Wk : (region == 2) ? Wv
                     : (region == 4) ? Wsk : (region == 5) ? W1 : W2;
      v = W[(size_t)k * 256 + n];
    }
    const __bf16 bv16 = f2bf(v);
    if (region < 5) WTall[(size_t)region * 65536 + idx] = bv16;
    else if (region == 5) WT1[idx] = bv16;
    else WT2[idx] = bv16;
  } else if (b < 1797) {
    const int j = (b - 1792) * 256 + tid;
    if (j < 1280) {
      float v = 0.f;
      if (j < 256) v = bq[j];
      else if (j < 512) v = bk[j - 256];
      else if (j < 768) v = bv[j - 512];
      else if (j < 1024) {
        const int col = j - 768, h = col >> 5, d = col & 31;
        const float* bqh = bq + h * 32;
        const float* we = We + (size_t)d * 256 + h * 32;
        float s = 0.f;
#pragma unroll
        for (int c = 0; c < 32; ++c) s += bqh[c] * we[c];
        v = s;
      }
      ball[j] = v;
    }
  } else if (b < 1829) {
    const int idx = (b - 1797) * 256 + tid;  // < 8192
    const int ch = idx >> 5, d = idx & 31;
    WeT[idx] = We[(size_t)d * 256 + ch];
  } else if (b < PREP_XB_END) {
    const int t = (b - 1829) * 256 + tid;
    if (t < NN * 256 / 8) {
      const float* p = x + (size_t)t * 8;
      float4v f0 = *(const float4v*)(p);
      float4v f1 = *(const float4v*)(p + 4);
      bf16x8 o;
#pragma unroll
      for (int j = 0; j < 4; ++j) { o[j] = f2bf(f0[j]); o[j + 4] = f2bf(f1[j]); }
      *(bf16x8*)(xb + (size_t)t * 8) = o;
    }
  } else {
    const int idx = (b - PREP_XB_END) * 256 + tid;
    if (idx < 2 * NN) degz[idx] = 0;
  }
}

// ---------------- CSR build ----------------
__global__ void count_deg_kernel(const int* __restrict__ dst, int* __restrict__ deg, int E) {
  int e = blockIdx.x * 256 + threadIdx.x;
  if (e < E) atomicAdd(&deg[dst[e]], 1);
}

// fused offs: block computes its exclusive base by redundant sum of deg[0..blk*256)
// then intra-block scan. 1 kernel replaces psum+scan+offs; no cross-block sync.
__global__ __launch_bounds__(256) void offs_fused_kernel(const int* __restrict__ deg,
                                                         int* __restrict__ offs, int n) {
  __shared__ int tmp[256];
  __shared__ int sbase[4];
  const int t = threadIdx.x;
  const int lim = blockIdx.x * 256;
  int bp = 0;
  for (int idx = t; idx < lim; idx += 256) bp += deg[idx];
#pragma unroll
  for (int s = 1; s < 64; s <<= 1) bp += __shfl_xor(bp, s);
  if ((t & 63) == 0) sbase[t >> 6] = bp;
  const int i = lim + t;
  int v = (i < n) ? deg[i] : 0;
  tmp[t] = v;
  __syncthreads();
  const int base = sbase[0] + sbase[1] + sbase[2] + sbase[3];
  for (int s = 1; s < 256; s <<= 1) {
    int u = (t >= s) ? tmp[t - s] : 0;
    __syncthreads();
    tmp[t] += u;
    __syncthreads();
  }
  if (i < n) offs[i] = base + tmp[t] - v;
  if (blockIdx.x == gridDim.x - 1 && t == 0) offs[n] = NE;
}

// scatter + fused ea permute: coalesced fp32 ea read (e sequential), bf16
// convert, scattered 64B write to CSR slot (random WRITES are fire-and-forget).
__global__ void scatter_kernel(const int* __restrict__ srcIn, const int* __restrict__ dstIn,
                               const float* __restrict__ ea,
                               const int* __restrict__ offs, int* __restrict__ cursor,
                               int* __restrict__ srcs, __bf16* __restrict__ eaC, int E) {
  int e = blockIdx.x * 256 + threadIdx.x;
  if (e >= E) return;
  const float* src = ea + (size_t)e * 32;
  float4v f[8];
#pragma unroll
  for (int t = 0; t < 8; ++t) f[t] = *(const float4v*)(src + t * 4);
  int d = dstIn[e];
  int p = atomicAdd(&cursor[d], 1);
  int o = offs[d] + p;
  srcs[o] = srcIn[e];
  __bf16* dstp = eaC + (size_t)o * 32;
#pragma unroll
  for (int t = 0; t < 4; ++t) {
    bf16x8 b;
#pragma unroll
    for (int j = 0; j < 4; ++j) { b[j] = f2bf(f[t * 2][j]); b[j + 4] = f2bf(f[t * 2 + 1][j]); }
    *(bf16x8*)(dstp + t * 8) = b;
  }
}

// ---------------- MFMA GEMM v6: TN tiling + software-pipelined A-loads -------
// TN=128 for big fused GEMM (R13: TN=64 regressed), TN=64 for MLP (R11 win).
// NEW: rotating 4-deep register buffer for A loads — step s+4's global loads
// issue while step s computes (8 loads in flight), hiding the ~200-500cy
// A-load latency that made all GEMMs latency-bound (R10/R13 counters).
template <int GX, int EPI, int MODE, int TN>
__global__ __launch_bounds__(256) void gemm_k4(
    const __bf16* __restrict__ A, const __bf16* __restrict__ Wt,
    const float* __restrict__ bias,
    float* __restrict__ Yf, __bf16* __restrict__ Ybf,
    __bf16* __restrict__ QGp, __bf16* __restrict__ KVp,
    const float* __restrict__ resid, int M, int gyTiles) {
  constexpr int XT = (GX * 128) / TN;   // col-tiles
  constexpr int NT = TN / 16;           // MFMA col frags per wave
  constexpr int CST = TN + 4;           // C-stage stride (floats)
  constexpr size_t SM_B = (size_t)TN * 264 * 2;
  constexpr size_t SM_C = (size_t)4 * 32 * CST * 4;
  constexpr size_t SMEM = SM_B > SM_C ? SM_B : SM_C;
  __shared__ __attribute__((aligned(16))) char smem[SMEM];
  __bf16* Bs = (__bf16*)smem;
  const int bid = blockIdx.x;
  const int stripe = bid / (8 * XT);
  const int rem = bid % (8 * XT);
  const int y8 = rem % 8;   // XCD id: col-blocks of one row-stripe share an XCD
  const int xt = rem / 8;
  const int y = stripe * 8 + y8;
  if (y >= gyTiles) return;
  const int n0 = xt * TN;

  {
    const int t = threadIdx.x;
#pragma unroll
    for (int i = 0; i < TN / 8; ++i) {  // TN*32 chunks / 256 threads
      int g = i * 256 + t;
      int row = g >> 5;
      int c16 = g & 31;
      bf16x8 v = *(const bf16x8*)(Wt + (size_t)(n0 + row) * 256 + c16 * 8);
      *(bf16x8*)(Bs + row * 264 + c16 * 8) = v;
    }
  }
  __syncthreads();

  const int lane = threadIdx.x & 63;
  const int w = threadIdx.x >> 6;
  const int r = lane & 15;
  const int q = lane >> 4;
  const int mw = y * 128 + w * 32;
  int ar0 = mw + r;      if (ar0 >= M) ar0 = M - 1;
  int ar1 = mw + 16 + r; if (ar1 >= M) ar1 = M - 1;
  const int kq = q * 8;
  const __bf16* A0 = A + (size_t)ar0 * 256 + kq;
  const __bf16* A1 = A + (size_t)ar1 * 256 + kq;

  float4v acc[2][NT];
#pragma unroll
  for (int i = 0; i < 2; ++i)
#pragma unroll
    for (int t = 0; t < NT; ++t) acc[i][t] = (float4v){0.f, 0.f, 0.f, 0.f};

  constexpr int HD = 4;  // A-load pipeline depth (K-steps)
  bf16x8 a0v[HD], a1v[HD];
#pragma unroll
  for (int s = 0; s < HD; ++s) {
    a0v[s] = *(const bf16x8*)(A0 + s * 32);
    a1v[s] = *(const bf16x8*)(A1 + s * 32);
  }

#pragma unroll
  for (int s = 0; s < 8; ++s) {
    const bf16x8 a0 = a0v[s % HD];
    const bf16x8 a1 = a1v[s % HD];
    if (s + HD < 8) {
      a0v[s % HD] = *(const bf16x8*)(A0 + (s + HD) * 32);
      a1v[s % HD] = *(const bf16x8*)(A1 + (s + HD) * 32);
    }
    const int ka = s * 32 + kq;
    bf16x8 b[NT];
#pragma unroll
    for (int t = 0; t < NT; ++t)
      b[t] = *(const bf16x8*)(Bs + (t * 16 + r) * 264 + ka);
#pragma unroll
    for (int t = 0; t < NT; ++t) {
      acc[0][t] = __builtin_amdgcn_mfma_f32_16x16x32_bf16(a0, b[t], acc[0][t], 0, 0, 0);
      acc[1][t] = __builtin_amdgcn_mfma_f32_16x16x32_bf16(a1, b[t], acc[1][t], 0, 0, 0);
    }
  }
  __syncthreads();  // B-tile dead; reuse LDS as C-stage

  // stage C (fp32, stride CST) with bias/gelu applied
  float* cs = (float*)smem + w * 32 * CST;
#pragma unroll
  for (int t = 0; t < NT; ++t) {
    const int col = n0 + t * 16 + r;
    const float bb = bias ? bias[col] : 0.0f;
#pragma unroll
    for (int i2 = 0; i2 < 2; ++i2)
#pragma unroll
      for (int ii = 0; ii < 4; ++ii) {
        float v = acc[i2][t][ii] + bb;
        if constexpr (EPI == 2 || EPI == 3) v = gelu_tanh(v);
        cs[(i2 * 16 + q * 4 + ii) * CST + t * 16 + r] = v;
      }
  }

  // coalesced read-back + vector stores (per-wave region; same-wave LDS order ok)
  constexpr int NSTR = GX * 128;
  constexpr int RPI = 256 / TN;   // rows per iter
  constexpr int LPR = TN / 4;     // lanes per row
  const int p = n0 >> 8;
  const int cbase = n0 & 255;
  __bf16* dstI = (p == 0 || p == 3) ? QGp : KVp;
  const int moff = (p >= 2) ? 4 : 0;  // planes 2(V),3(G) are second member
#pragma unroll
  for (int i = 0; i < 32 / RPI; ++i) {
    const int rl = i * RPI + lane / LPR;
    const int row = mw + rl;
    const int c4 = (lane % LPR) * 4;
    float4v v = *(const float4v*)(cs + rl * CST + c4);
    if (row < M) {
      if constexpr (MODE == 1) {
        if (p == 4) {
          *(float4v*)(Yf + (size_t)row * 256 + cbase + c4) = v;
        } else {
          bf16x4 b4;
          b4[0] = f2bf(v[0]); b4[1] = f2bf(v[1]); b4[2] = f2bf(v[2]); b4[3] = f2bf(v[3]);
          const int c = cbase + c4;
          *(bf16x4*)(dstI + (size_t)row * 512 + 2 * c + moff) = b4;
        }
      } else if constexpr (EPI == 1) {
        *(float4v*)(Yf + (size_t)row * NSTR + n0 + c4) = v;
      } else if constexpr (EPI == 3) {
        float4v rr = *(const float4v*)(resid + (size_t)row * NSTR + n0 + c4);
        v[0] += rr[0]; v[1] += rr[1]; v[2] += rr[2]; v[3] += rr[3];
        *(float4v*)(Yf + (size_t)row * NSTR + n0 + c4) = v;
      } else {  // bf16 out
        bf16x4 b4;
        b4[0] = f2bf(v[0]); b4[1] = f2bf(v[1]); b4[2] = f2bf(v[2]); b4[3] = f2bf(v[3]);
        *(bf16x4*)(Ybf + (size_t)row * NSTR + n0 + c4) = b4;
      }
    }
  }
}

// ---------------- attention (v5 exact, proven 61us): 4 waves/node, direct
// per-edge srcs loads, 2-edge unroll (i, i+4), single random-gather stream
// (KV); eaC CSR-ordered sequential; exp2 with prefolded scale; wave-0 epilogue.
__global__ __launch_bounds__(256) void attn_kernel(
    const __bf16* __restrict__ QG, const __bf16* __restrict__ KV,
    const __bf16* __restrict__ eaC,
    const int* __restrict__ srcs, const int* __restrict__ offs,
    float* __restrict__ OUT, __bf16* __restrict__ AE) {
  __shared__ float sdn[4][64];
  __shared__ float sav[4][64][4], sae[4][64][4];
  const int lane = threadIdx.x & 63;
  const int w = threadIdx.x >> 6;
  const int n = blockIdx.x;
  const int sub = lane & 7;

  // fold 1/sqrt(32) * log2(e) into q,g once
  const float LSC = 0.25506589858f;
  const bf16x8 qg = *(const bf16x8*)(QG + (size_t)n * 512 + lane * 8);
  const float q0 = bf2f(qg[0]) * LSC, q1 = bf2f(qg[1]) * LSC;
  const float q2 = bf2f(qg[2]) * LSC, q3 = bf2f(qg[3]) * LSC;
  const float g0 = bf2f(qg[4]) * LSC, g1 = bf2f(qg[5]) * LSC;
  const float g2 = bf2f(qg[6]) * LSC, g3 = bf2f(qg[7]) * LSC;

  float denom = 0.f;
  float4v accv = {0.f, 0.f, 0.f, 0.f};
  float4v acce = {0.f, 0.f, 0.f, 0.f};
  const int beg = offs[n], end = offs[n + 1];

  int i = beg + w;
  for (; i + 4 < end; i += 8) {  // pair: edges i and i+4
    const int s0 = srcs[i];
    const int s1 = srcs[i + 4];
    const bf16x8 kv0 = *(const bf16x8*)(KV + (size_t)s0 * 512 + lane * 8);
    const bf16x4 a0 = *(const bf16x4*)(eaC + (size_t)i * 32 + sub * 4);
    const bf16x8 kv1 = *(const bf16x8*)(KV + (size_t)s1 * 512 + lane * 8);
    const bf16x4 a1 = *(const bf16x4*)(eaC + (size_t)(i + 4) * 32 + sub * 4);
    const float e00 = bf2f(a0[0]), e01 = bf2f(a0[1]), e02 = bf2f(a0[2]), e03 = bf2f(a0[3]);
    const float e10 = bf2f(a1[0]), e11 = bf2f(a1[1]), e12 = bf2f(a1[2]), e13 = bf2f(a1[3]);
    float p0 = q0 * bf2f(kv0[0]) + q1 * bf2f(kv0[1]) + q2 * bf2f(kv0[2]) + q3 * bf2f(kv0[3])
             + g0 * e00 + g1 * e01 + g2 * e02 + g3 * e03;
    float p1 = q0 * bf2f(kv1[0]) + q1 * bf2f(kv1[1]) + q2 * bf2f(kv1[2]) + q3 * bf2f(kv1[3])
             + g0 * e10 + g1 * e11 + g2 * e12 + g3 * e13;
    p0 += __shfl_xor(p0, 1); p1 += __shfl_xor(p1, 1);
    p0 += __shfl_xor(p0, 2); p1 += __shfl_xor(p1, 2);
    p0 += __shfl_xor(p0, 4); p1 += __shfl_xor(p1, 4);
    const float w0 = exp2f(p0);
    const float w1 = exp2f(p1);
    denom += w0 + w1;
    accv[0] += w0 * bf2f(kv0[4]) + w1 * bf2f(kv1[4]);
    accv[1] += w0 * bf2f(kv0[5]) + w1 * bf2f(kv1[5]);
    accv[2] += w0 * bf2f(kv0[6]) + w1 * bf2f(kv1[6]);
    accv[3] += w0 * bf2f(kv0[7]) + w1 * bf2f(kv1[7]);
    acce[0] += w0 * e00 + w1 * e10;
    acce[1] += w0 * e01 + w1 * e11;
    acce[2] += w0 * e02 + w1 * e12;
    acce[3] += w0 * e03 + w1 * e13;
  }
  if (i < end) {
    const int s0 = srcs[i];
    const bf16x8 kv0 = *(const bf16x8*)(KV + (size_t)s0 * 512 + lane * 8);
    const bf16x4 a0 = *(const bf16x4*)(eaC + (size_t)i * 32 + sub * 4);
    const float e00 = bf2f(a0[0]), e01 = bf2f(a0[1]), e02 = bf2f(a0[2]), e03 = bf2f(a0[3]);
    float p0 = q0 * bf2f(kv0[0]) + q1 * bf2f(kv0[1]) + q2 * bf2f(kv0[2]) + q3 * bf2f(kv0[3])
             + g0 * e00 + g1 * e01 + g2 * e02 + g3 * e03;
    p0 += __shfl_xor(p0, 1);
    p0 += __shfl_xor(p0, 2);
    p0 += __shfl_xor(p0, 4);
    const float w0 = exp2f(p0);
    denom += w0;
    accv[0] += w0 * bf2f(kv0[4]);
    accv[1] += w0 * bf2f(kv0[5]);
    accv[2] += w0 * bf2f(kv0[6]);
    accv[3] += w0 * bf2f(kv0[7]);
    acce[0] += w0 * e00;
    acce[1] += w0 * e01;
    acce[2] += w0 * e02;
    acce[3] += w0 * e03;
  }

  sdn[w][lane] = denom;
#pragma unroll
  for (int j = 0; j < 4; ++j) { sav[w][lane][j] = accv[j]; sae[w][lane][j] = acce[j]; }
  __syncthreads();
  if (w == 0) {
    float D = 0.f;
    float4v av = {0.f, 0.f, 0.f, 0.f};
    float4v ae = {0.f, 0.f, 0.f, 0.f};
#pragma unroll
    for (int ww = 0; ww < 4; ++ww) {
      D += sdn[ww][lane];
#pragma unroll
      for (int j = 0; j < 4; ++j) { av[j] += sav[ww][lane][j]; ae[j] += sae[ww][lane][j]; }
    }
    const float inv = 1.0f / (D + 1e-16f);
    const int c0 = lane * 4;
    float4v o = *(const float4v*)(OUT + (size_t)n * 256 + c0);
#pragma unroll
    for (int j = 0; j < 4; ++j) o[j] += av[j] * inv;
    *(float4v*)(OUT + (size_t)n * 256 + c0) = o;
    bf16x4 aeb;
    aeb[0] = f2bf(ae[0] * inv); aeb[1] = f2bf(ae[1] * inv);
    aeb[2] = f2bf(ae[2] * inv); aeb[3] = f2bf(ae[3] * inv);
    *(bf16x4*)(AE + (size_t)n * 256 + c0) = aeb;
  }
}

// ---------------- post: OUT += AE@We (per-head); OUTh = bf16(OUT) ----------------
__global__ __launch_bounds__(256) void post_kernel(
    const __bf16* __restrict__ AE, const float* __restrict__ WeT,
    float* __restrict__ OUT, __bf16* __restrict__ OUTh) {
  const int lane = threadIdx.x & 63;
  const int wave = threadIdx.x >> 6;
  const int c0 = lane * 4;
  const int hg = lane >> 3;

  float4v w4[4][8];
#pragma unroll
  for (int j = 0; j < 4; ++j)
#pragma unroll
    for (int s = 0; s < 8; ++s)
      w4[j][s] = *(const float4v*)(WeT + (size_t)(c0 + j) * 32 + s * 4);

  const int nbase = blockIdx.x * 64;
  for (int it = 0; it < 16; ++it) {
    const int n = nbase + it * 4 + wave;
    if (n >= NN) return;
    const __bf16* aerow = AE + (size_t)n * HIDDEN + hg * 32;
    float aef[32];
#pragma unroll
    for (int t = 0; t < 4; ++t) {
      bf16x8 a8 = *(const bf16x8*)(aerow + t * 8);
#pragma unroll
      for (int j = 0; j < 8; ++j) aef[t * 8 + j] = bf2f(a8[j]);
    }
    float4v o = *(const float4v*)(OUT + (size_t)n * HIDDEN + c0);
#pragma unroll
    for (int j = 0; j < 4; ++j) {
      float s = 0.f;
#pragma unroll
      for (int g = 0; g < 8; ++g) {
        s += aef[g * 4 + 0] * w4[j][g][0] + aef[g * 4 + 1] * w4[j][g][1]
           + aef[g * 4 + 2] * w4[j][g][2] + aef[g * 4 + 3] * w4[j][g][3];
      }
      o[j] += s;
    }
    *(float4v*)(OUT + (size_t)n * HIDDEN + c0) = o;
    bf16x4 ob;
    ob[0] = f2bf(o[0]); ob[1] = f2bf(o[1]); ob[2] = f2bf(o[2]); ob[3] = f2bf(o[3]);
    *(bf16x4*)(OUTh + (size_t)n * HIDDEN + c0) = ob;
  }
}

extern "C" void kernel_launch(void* const* d_in, const int* in_sizes, int n_in,
                              void* d_out, int out_size, void* d_ws, size_t ws_size,
                              hipStream_t stream) {
  (void)in_sizes; (void)n_in; (void)out_size; (void)ws_size;
  const float* x   = (const float*)d_in[0];
  const int*   ei  = (const int*)d_in[1];
  const float* ea  = (const float*)d_in[2];
  const float* Wq  = (const float*)d_in[3];
  const float* bq  = (const float*)d_in[4];
  const float* Wk  = (const float*)d_in[5];
  const float* bk  = (const float*)d_in[6];
  const float* Wv  = (const float*)d_in[7];
  const float* bv  = (const float*)d_in[8];
  const float* We  = (const float*)d_in[9];
  const float* Wsk = (const float*)d_in[10];
  const float* W1  = (const float*)d_in[11];
  const float* b1  = (const float*)d_in[12];
  const float* W2  = (const float*)d_in[13];
  const float* b2  = (const float*)d_in[14];
  float* out = (float*)d_out;

  char* ws = (char*)d_ws;
  size_t off = 0;
  auto alloc = [&](size_t bytes) -> char* {
    off = (off + 255) & ~(size_t)255;
    char* p = ws + off;
    off += bytes;
    return p;
  };
  __bf16* QG   = (__bf16*)alloc((size_t)NN * 512 * 2);
  __bf16* KV   = (__bf16*)alloc((size_t)NN * 512 * 2);
  __bf16* xb   = (__bf16*)alloc((size_t)NN * 256 * 2);
  __bf16* AE   = (__bf16*)alloc((size_t)NN * 256 * 2);      // reused as H1
  __bf16* OUTh = (__bf16*)alloc((size_t)NN * 256 * 2);
  __bf16* eaC  = (__bf16*)alloc((size_t)NE * 32 * 2);
  __bf16* WTall = (__bf16*)alloc((size_t)1280 * 256 * 2);
  __bf16* WT1  = (__bf16*)alloc(256 * 256 * 2);
  __bf16* WT2  = (__bf16*)alloc(256 * 256 * 2);
  float*  ball = (float*)alloc(1280 * 4);
  float*  WeT  = (float*)alloc(256 * 32 * 4);
  int* deg    = (int*)alloc((size_t)2 * NN * 4);
  int* cursor = deg + NN;
  int* offs   = (int*)alloc((size_t)(NN + 1) * 4);
  int* srcs   = (int*)alloc((size_t)NE * 4);
  __bf16* H1 = AE;

  const int* srcIn = ei;       // edge_index[0]
  const int* dstIn = ei + NE;  // edge_index[1]

  // ---- fused prep (weights + x->bf16 + zero deg/cursor) ----
  const int prepBlocks = PREP_XB_END + (2 * NN + 255) / 256;
  prep_kernel<<<prepBlocks, 256, 0, stream>>>(Wq, Wk, Wv, Wsk, W1, W2, We, bq, bk, bv, x,
                                              WTall, WT1, WT2, ball, WeT, xb, deg);

  // ---- CSR build (count -> fused offs -> scatter+ea permute) ----
  const int nb = (NN + 255) / 256;  // 118
  count_deg_kernel<<<(NE + 255) / 256, 256, 0, stream>>>(dstIn, deg, NE);
  offs_fused_kernel<<<nb, 256, 0, stream>>>(deg, offs, NN);
  scatter_kernel<<<(NE + 255) / 256, 256, 0, stream>>>(srcIn, dstIn, ea, offs, cursor,
                                                       srcs, eaC, NE);

  const int gy = (NN + 127) / 128;          // 235
  const int stripes = (gy + 7) / 8;         // 30
  // ---- fused node GEMM: TN=128 (R13: TN=64 regressed) + pipelined A-loads ----
  gemm_k4<10, 0, 1, 128><<<stripes * 80, 256, 0, stream>>>(
      xb, WTall, ball, out, nullptr, QG, KV, nullptr, NN, gy);

  // ---- attention (RMW out, write AE): v5 structure, wave-0 epilogue ----
  attn_kernel<<<NN, 256, 0, stream>>>(QG, KV, eaC, srcs, offs, out, AE);

  // ---- post: out += AE @ We (per-head), OUTh = bf16(out) ----
  post_kernel<<<(NN + 63) / 64, 256, 0, stream>>>(AE, WeT, out, OUTh);

  // ---- MLP (TN=64: proven best — R11) + pipelined A-loads ----
  gemm_k4<2, 2, 0, 64><<<stripes * 32, 256, 0, stream>>>(
      OUTh, WT1, b1, nullptr, H1, nullptr, nullptr, nullptr, NN, gy);
  gemm_k4<2, 3, 0, 64><<<stripes * 32, 256, 0, stream>>>(
      H1, WT2, b2, out, nullptr, nullptr, nullptr, out, NN, gy);
}